// Round 17
// baseline (212.937 us; speedup 1.0000x reference)
//
#include <hip/hip_runtime.h>
#include <cstdint>
#include <cstddef>

#define MB_   4096
#define NK_   8
#define DM_   1024
#define DT_   128

typedef __bf16 bf16;
typedef __bf16 bf16x8 __attribute__((ext_vector_type(8)));
typedef __bf16 bf16x4 __attribute__((ext_vector_type(4)));
typedef float  f32x4  __attribute__((ext_vector_type(4)));

__device__ __forceinline__ void gload_lds16(const void* g, void* l) {
  __builtin_amdgcn_global_load_lds(
      (__attribute__((address_space(1))) void*)g,
      (__attribute__((address_space(3))) void*)l,
      16, 0, 0);
}

// chunk swizzle: logical 16B-chunk c of row r lives at LDS chunk c ^ hsw(r).
__device__ __forceinline__ int hsw(int r) { return (r ^ (r >> 2)) & 3; }

// ---------------------------------------------------------------------------
// merged prep: [0,8192) proj_w f32->bf16 | [8192,12288) w_vs transpose |
//              [12288,12416) attns = 1.0
__global__ void prep_kernel(const float* __restrict__ pw, bf16* __restrict__ pwb,
                            const float* __restrict__ wvs, bf16* __restrict__ wvt,
                            float* __restrict__ out) {
  int b = blockIdx.x;
  int tid = threadIdx.x;
  if (b < 8192) {
    size_t i = ((size_t)b * 256 + tid) * 4;
    float4 f = *(const float4*)&pw[i];
    bf16x4 o = { (bf16)f.x, (bf16)f.y, (bf16)f.z, (bf16)f.w };
    *(bf16x4*)&pwb[i] = o;
  } else if (b < 12288) {
    int o = (b - 8192) * 256 + tid;
    int d = o & 1023;
    int t = (o >> 10) & 127;
    int n = o >> 17;
    wvt[o] = (bf16)wvs[(size_t)n * 131072 + (size_t)d * 128 + t];
  } else {
    out[(size_t)33554432 + (size_t)(b - 12288) * 256 + tid] = 1.0f;
  }
}

// ---------------------------------------------------------------------------
// GEMM1 pipelined: v_s[n] = V_n[4096x1024](f32) @ WvT[n][128x1024]^T -> A2 (bf16).
// A: f32 regs (2-deep) -> bf16 ds_write, 2 LDS bufs. B: gload 2-ahead, 3 bufs.
// VB: additionally stream bf16(v) to vb (residual for LN; −67MB from ln pass).
// vmcnt accounting with VB store: 5 ops/iter -> boundary vmcnt(5)/(1).
template<bool VB>
__global__ __launch_bounds__(256, 2) void gemm1p_kernel(
    const float* __restrict__ vflat, const bf16* __restrict__ WvT,
    bf16* __restrict__ A2, bf16* __restrict__ vb)
{
  __shared__ __align__(16) bf16 Ab[2][2048];   // [buf][64*32]  4KB each
  __shared__ __align__(16) bf16 Bb[3][4096];   // [buf][128*32] 8KB each; 24KB total
  const int tid  = threadIdx.x;
  const int wave = tid >> 6, lane = tid & 63;
  const int wm = wave >> 1, wn = wave & 1;
  const int n  = blockIdx.y;
  const int b0 = blockIdx.x * 64;

  const int r  = tid >> 2;
  const int cs = (tid & 3) ^ hsw(r);

  const size_t vbase = ((size_t)(n * MB_ + b0 + r)) * 1024 + (tid & 3) * 8;
  const float* ag = vflat + vbase;
  const int awOff = r * 32 + cs * 8;
  const bf16* bg = WvT + (size_t)n * 131072 + (size_t)r * 1024 + cs * 8;
  const int bOff = wave * 1024;

  f32x4 ra[2][2];

  #define LOADA(t, bi)  { const float* p = ag + (t) * 32;                    \
                          ra[bi][0] = *(const f32x4*)p;                      \
                          ra[bi][1] = *(const f32x4*)(p + 4); }
  #define GLOADB(t, bi) { const bf16* p = bg + (size_t)(t) * 32;             \
                          char* d = (char*)Bb[bi] + bOff;                    \
                          gload_lds16(p, d);                                 \
                          gload_lds16(p + 64 * 1024, d + 4096); }
  #define WRITEA(bi, dst, tt) { f32x4 f0 = ra[bi][0], f1 = ra[bi][1];        \
    bf16x8 h = { (bf16)f0.x, (bf16)f0.y, (bf16)f0.z, (bf16)f0.w,             \
                 (bf16)f1.x, (bf16)f1.y, (bf16)f1.z, (bf16)f1.w };           \
    *(bf16x8*)&Ab[dst][awOff] = h;                                           \
    if (VB) *(bf16x8*)&vb[vbase + (size_t)(tt) * 32] = h; }

  LOADA(0, 0); GLOADB(0, 0); LOADA(1, 1); GLOADB(1, 1);
  WRITEA(0, 0, 0);
  if (VB) { asm volatile("s_waitcnt vmcnt(5)" ::: "memory"); }   // B(0) done (store outstanding ok? store is newest; B(0) older) -- conservative:
  else    { asm volatile("s_waitcnt vmcnt(4)" ::: "memory"); }
  asm volatile("s_waitcnt lgkmcnt(0)" ::: "memory");
  __builtin_amdgcn_s_barrier();
  __builtin_amdgcn_sched_barrier(0);

  f32x4 acc[2][4] = {};
  const int krow = lane & 15;
  const int cch  = lane >> 4;
  const int swoff = ((cch ^ hsw(krow)) << 4);

  #pragma unroll 2
  for (int t = 0; t < 32; ++t) {
    bf16x8 af[2], bfr[4];
    #pragma unroll
    for (int i = 0; i < 2; ++i)
      af[i] = *(const bf16x8*)((const char*)Ab[t & 1] + (wm * 32 + i * 16 + krow) * 64 + swoff);
    #pragma unroll
    for (int j = 0; j < 4; ++j)
      bfr[j] = *(const bf16x8*)((const char*)Bb[t % 3] + (wn * 64 + j * 16 + krow) * 64 + swoff);

    if (t < 31) WRITEA((t + 1) & 1, (t + 1) & 1, t + 1);
    if (t < 30) { LOADA(t + 2, t & 1); GLOADB(t + 2, (t + 2) % 3); }

    #pragma unroll
    for (int i = 0; i < 2; ++i)
      #pragma unroll
      for (int j = 0; j < 4; ++j)
        acc[i][j] = __builtin_amdgcn_mfma_f32_16x16x32_bf16(af[i], bfr[j], acc[i][j], 0, 0, 0);

    if (t < 31) {
      asm volatile("s_waitcnt lgkmcnt(0)" ::: "memory");
      if (VB) {
        if (t < 30)       { asm volatile("s_waitcnt vmcnt(5)" ::: "memory"); }
        else              { asm volatile("s_waitcnt vmcnt(1)" ::: "memory"); }
      } else {
        if (t < 30)       { asm volatile("s_waitcnt vmcnt(4)" ::: "memory"); }
        else              { asm volatile("s_waitcnt vmcnt(0)" ::: "memory"); }
      }
      __builtin_amdgcn_s_barrier();
      __builtin_amdgcn_sched_barrier(0);
    }
  }
  #undef LOADA
  #undef GLOADB
  #undef WRITEA

  // ---- epilogue: acc -> LDS stage -> coalesced A2 write ----
  __syncthreads();
  bf16* stage = &Bb[0][0];
  #pragma unroll
  for (int i = 0; i < 2; ++i) {
    #pragma unroll
    for (int j = 0; j < 4; ++j) {
      int t = wn * 64 + j * 16 + (lane & 15);
      #pragma unroll
      for (int rr = 0; rr < 4; ++rr) {
        int bl = wm * 32 + i * 16 + (lane >> 4) * 4 + rr;
        stage[bl * 128 + t] = (bf16)acc[i][j][rr];
      }
    }
  }
  __syncthreads();
  bf16* dst = A2 + ((size_t)(n * 512 + (b0 >> 3))) * 1024;
  #pragma unroll
  for (int k = 0; k < 4; ++k) {
    int c = tid + k * 256;
    *(bf16x8*)&dst[c * 8] = *(const bf16x8*)&stage[c * 8];
  }
}

// ---------------------------------------------------------------------------
// GEMM2 (best-of-session, round-4 schedule): x = A2 @ PW^T + pb.
template<bool ZB>
__global__ __launch_bounds__(512, 2) void gemm2p_kernel(
    const bf16* __restrict__ A2, const bf16* __restrict__ PW,
    const float* __restrict__ pb, void* __restrict__ xoutp)
{
  __shared__ __align__(16) bf16 As[4][8192];
  __shared__ __align__(16) bf16 Bs[4][8192];

  const int tid  = threadIdx.x;
  const int w    = tid >> 6;
  const int lane = tid & 63;
  const int wm   = w >> 2;
  const int wn   = w & 3;

  const int bid   = blockIdx.x;
  const int x     = bid & 7;
  const int local = bid >> 3;
  const int mt    = local & 15;
  const int nt    = x * 4 + (local >> 4);
  const int m0    = mt * 256;
  const int n0    = nt * 256;

  const int rS = tid >> 2;
  const int cS = (tid & 3) ^ hsw(rS);
  const char* aG0 = (const char*)A2 + (size_t)(m0 + rS) * 2048 + cS * 16;
  const char* aG1 = aG0 + (size_t)128 * 2048;
  const char* bG0 = (const char*)PW + (size_t)(n0 + rS) * 2048 + cS * 16;
  const char* bG1 = bG0 + (size_t)128 * 2048;

  #define STAGE_A(t) { char* d = (char*)As[(t) & 3] + tid * 16;            \
                       gload_lds16(aG0 + (t) * 64, d);                      \
                       gload_lds16(aG1 + (t) * 64, d + 8192); }
  #define STAGE_B(t) { char* d = (char*)Bs[(t) & 3] + tid * 16;            \
                       gload_lds16(bG0 + (t) * 64, d);                      \
                       gload_lds16(bG1 + (t) * 64, d + 8192); }

  STAGE_A(0); STAGE_B(0); STAGE_A(1); STAGE_B(1);
  asm volatile("s_waitcnt vmcnt(4)" ::: "memory");
  __builtin_amdgcn_sched_barrier(0);
  __builtin_amdgcn_s_barrier();

  f32x4 acc[8][4] = {};
  const int fr = lane & 15;
  const int g  = lane >> 4;
  const int swoff = ((g ^ hsw(fr)) << 4);
  const int aRd = (wm * 128 + fr) * 64 + swoff;
  const int bRd = (wn * 64  + fr) * 64 + swoff;

  #pragma unroll 4
  for (int t = 0; t < 32; ++t) {
    const char* pA = (const char*)As[t & 3] + aRd;
    const char* pB = (const char*)Bs[t & 3] + bRd;

    bf16x8 a[4], b[4];
    #pragma unroll
    for (int m = 0; m < 4; ++m) a[m] = *(const bf16x8*)(pA + m * 1024);
    #pragma unroll
    for (int n = 0; n < 4; ++n) b[n] = *(const bf16x8*)(pB + n * 1024);
    if (t < 30) STAGE_A(t + 2);
    __builtin_amdgcn_s_barrier();
    __builtin_amdgcn_s_setprio(1);
    #pragma unroll
    for (int m = 0; m < 4; ++m)
      #pragma unroll
      for (int n = 0; n < 4; ++n)
        acc[m][n] = __builtin_amdgcn_mfma_f32_16x16x32_bf16(a[m], b[n], acc[m][n], 0, 0, 0);
    __builtin_amdgcn_s_setprio(0);
    __builtin_amdgcn_s_barrier();

    bf16x8 a2[4];
    #pragma unroll
    for (int m = 0; m < 4; ++m) a2[m] = *(const bf16x8*)(pA + (4 + m) * 1024);
    if (t < 30) STAGE_B(t + 2);
    __builtin_amdgcn_s_barrier();
    __builtin_amdgcn_s_setprio(1);
    #pragma unroll
    for (int m = 0; m < 4; ++m)
      #pragma unroll
      for (int n = 0; n < 4; ++n)
        acc[4 + m][n] = __builtin_amdgcn_mfma_f32_16x16x32_bf16(a2[m], b[n], acc[4 + m][n], 0, 0, 0);
    __builtin_amdgcn_s_setprio(0);
    if (t < 30)       { asm volatile("s_waitcnt vmcnt(4)" ::: "memory"); }
    else if (t == 30) { asm volatile("s_waitcnt vmcnt(0)" ::: "memory"); }
    __builtin_amdgcn_sched_barrier(0);
    __builtin_amdgcn_s_barrier();
  }
  #undef STAGE_A
  #undef STAGE_B

  #pragma unroll
  for (int m = 0; m < 8; ++m) {
    #pragma unroll
    for (int n = 0; n < 4; ++n) {
      int nn = n0 + wn * 64 + n * 16 + fr;
      float pbn = pb[nn];
      #pragma unroll
      for (int r = 0; r < 4; ++r) {
        int mm = m0 + wm * 128 + m * 16 + g * 4 + r;
        size_t off = (size_t)mm * 8192 + nn;
        float val = acc[m][n][r] + pbn;
        if (ZB) ((bf16*)xoutp)[off] = (bf16)val;
        else    ((float*)xoutp)[off] = val;
      }
    }
  }
}

// ---------------------------------------------------------------------------
// LN over 1024-wide rows: x = z + v(residual); ddof=1, eps outside sqrt.
// VB: residual from the bf16 copy (67MB) instead of f32 v (134MB).
template<bool ZB, bool VB>
__global__ __launch_bounds__(256) void ln_kernel(
    const void* zin, const float* __restrict__ vres, const bf16* __restrict__ vb,
    const float* __restrict__ gamma, const float* __restrict__ beta,
    float* outp)
{
  __shared__ float red[16];
  const int row = blockIdx.x;
  const int tid = threadIdx.x;
  const size_t base = (size_t)row * 1024 + tid * 4;

  float4 rv;
  if (VB) {
    bf16x4 vb4 = *(const bf16x4*)(vb + base);
    rv.x = (float)vb4[0]; rv.y = (float)vb4[1];
    rv.z = (float)vb4[2]; rv.w = (float)vb4[3];
  } else {
    rv = *(const float4*)&vres[base];
  }
  float4 x;
  if (ZB) {
    bf16x4 zb4 = *(const bf16x4*)((const bf16*)zin + base);
    x.x = (float)zb4[0] + rv.x; x.y = (float)zb4[1] + rv.y;
    x.z = (float)zb4[2] + rv.z; x.w = (float)zb4[3] + rv.w;
  } else {
    float4 zf = *(const float4*)((const float*)zin + base);
    x.x = zf.x + rv.x; x.y = zf.y + rv.y; x.z = zf.z + rv.z; x.w = zf.w + rv.w;
  }

  float s  = x.x + x.y + x.z + x.w;
  float ss = x.x * x.x + x.y * x.y + x.z * x.z + x.w * x.w;
  #pragma unroll
  for (int m = 32; m >= 1; m >>= 1) {
    s  += __shfl_xor(s,  m, 64);
    ss += __shfl_xor(ss, m, 64);
  }
  const int wave = tid >> 6, lane = tid & 63;
  if (lane == 0) { red[wave] = s; red[wave + 8] = ss; }
  __syncthreads();
  float S  = red[0] + red[1] + red[2] + red[3];
  float SS = red[8] + red[9] + red[10] + red[11];
  float mu  = S * (1.0f / 1024.0f);
  float var = (SS - 1024.0f * mu * mu) * (1.0f / 1023.0f);
  var = var < 0.0f ? 0.0f : var;
  float rs = 1.0f / (sqrtf(var) + 1e-3f);
  float4 gmv = *(const float4*)&gamma[tid * 4];
  float4 be  = *(const float4*)&beta[tid * 4];
  float4 y;
  y.x = (x.x - mu) * rs * gmv.x + be.x;
  y.y = (x.y - mu) * rs * gmv.y + be.y;
  y.z = (x.z - mu) * rs * gmv.z + be.z;
  y.w = (x.w - mu) * rs * gmv.w + be.w;
  *(float4*)&outp[base] = y;
}

// ---------------------------------------------------------------------------
extern "C" void kernel_launch(void* const* d_in, const int* in_sizes, int n_in,
                              void* d_out, int out_size, void* d_ws, size_t ws_size,
                              hipStream_t stream) {
  const float* v     = (const float*)d_in[2];
  const float* wvs   = (const float*)d_in[5];
  const float* pw    = (const float*)d_in[6];
  const float* pb    = (const float*)d_in[7];
  const float* gamma = (const float*)d_in[8];
  const float* beta  = (const float*)d_in[9];
  float* out = (float*)d_out;

  // ws: PW bf16 16M | WvT bf16 2M | A2 bf16 8M | x bf16 64M | vb bf16 64M
  const size_t OFF_WVT = 16777216;
  const size_t OFF_A2  = OFF_WVT + 2097152;
  const size_t OFF_X   = OFF_A2 + 8388608;
  const size_t OFF_VB  = OFF_X + 67108864;
  const size_t NEED_ZB = OFF_VB;
  const size_t NEED_VB = OFF_VB + 67108864;

  bf16* PWb  = (bf16*)d_ws;
  bf16* WvT  = (bf16*)((char*)d_ws + OFF_WVT);
  bf16* A2   = (bf16*)((char*)d_ws + OFF_A2);
  bf16* VB16 = (bf16*)((char*)d_ws + OFF_VB);
  const bool zb  = (ws_size >= NEED_ZB);
  const bool vbe = (ws_size >= NEED_VB) && zb;
  void* xbuf = zb ? (void*)((char*)d_ws + OFF_X) : (void*)out;

  hipLaunchKernelGGL(prep_kernel, dim3(12416), dim3(256), 0, stream, pw, PWb, wvs, WvT, out);
  if (vbe)
    hipLaunchKernelGGL((gemm1p_kernel<true>),  dim3(64, 8), dim3(256), 0, stream, v, WvT, A2, VB16);
  else
    hipLaunchKernelGGL((gemm1p_kernel<false>), dim3(64, 8), dim3(256), 0, stream, v, WvT, A2, VB16);

  if (zb) {
    hipLaunchKernelGGL((gemm2p_kernel<true>),  dim3(512), dim3(512), 0, stream, A2, PWb, pb, xbuf);
    if (vbe)
      hipLaunchKernelGGL((ln_kernel<true, true>),  dim3(32768), dim3(256), 0, stream, xbuf, v, VB16, gamma, beta, out);
    else
      hipLaunchKernelGGL((ln_kernel<true, false>), dim3(32768), dim3(256), 0, stream, xbuf, v, VB16, gamma, beta, out);
  } else {
    hipLaunchKernelGGL((gemm2p_kernel<false>), dim3(512), dim3(512), 0, stream, A2, PWb, pb, xbuf);
    hipLaunchKernelGGL((ln_kernel<false, false>), dim3(32768), dim3(256), 0, stream, xbuf, v, VB16, gamma, beta, out);
  }
}

// Round 18
// 190.564 us; speedup vs baseline: 1.1174x; 1.1174x over previous
//
#include <hip/hip_runtime.h>
#include <cstdint>
#include <cstddef>

#define MB_   4096
#define NK_   8
#define DM_   1024
#define DT_   128

typedef __bf16 bf16;
typedef __bf16 bf16x8 __attribute__((ext_vector_type(8)));
typedef __bf16 bf16x4 __attribute__((ext_vector_type(4)));
typedef float  f32x4  __attribute__((ext_vector_type(4)));

__device__ __forceinline__ void gload_lds16(const void* g, void* l) {
  __builtin_amdgcn_global_load_lds(
      (__attribute__((address_space(1))) void*)g,
      (__attribute__((address_space(3))) void*)l,
      16, 0, 0);
}

// chunk swizzle: logical 16B-chunk c of row r lives at LDS chunk c ^ hsw(r).
__device__ __forceinline__ int hsw(int r) { return (r ^ (r >> 2)) & 3; }

// ---------------------------------------------------------------------------
// merged prep: [0,8192) proj_w f32->bf16 | [8192,12288) w_vs transpose |
//              [12288,12416) attns = 1.0
__global__ void prep_kernel(const float* __restrict__ pw, bf16* __restrict__ pwb,
                            const float* __restrict__ wvs, bf16* __restrict__ wvt,
                            float* __restrict__ out) {
  int b = blockIdx.x;
  int tid = threadIdx.x;
  if (b < 8192) {
    size_t i = ((size_t)b * 256 + tid) * 4;
    float4 f = *(const float4*)&pw[i];
    bf16x4 o = { (bf16)f.x, (bf16)f.y, (bf16)f.z, (bf16)f.w };
    *(bf16x4*)&pwb[i] = o;
  } else if (b < 12288) {
    int o = (b - 8192) * 256 + tid;
    int d = o & 1023;
    int t = (o >> 10) & 127;
    int n = o >> 17;
    wvt[o] = (bf16)wvs[(size_t)n * 131072 + (size_t)d * 128 + t];
  } else {
    out[(size_t)33554432 + (size_t)(b - 12288) * 256 + tid] = 1.0f;
  }
}

// ---------------------------------------------------------------------------
// GEMM1 pipelined: v_s[n] = V_n[4096x1024](f32) @ WvT[n][128x1024]^T -> A2 (bf16).
// A: f32 regs (2-deep) -> bf16 ds_write, 2 LDS bufs. B: gload 2-ahead, 3 bufs.
__global__ __launch_bounds__(256, 2) void gemm1p_kernel(
    const float* __restrict__ vflat, const bf16* __restrict__ WvT,
    bf16* __restrict__ A2)
{
  __shared__ __align__(16) bf16 Ab[2][2048];   // [buf][64*32]  4KB each
  __shared__ __align__(16) bf16 Bb[3][4096];   // [buf][128*32] 8KB each
  const int tid  = threadIdx.x;
  const int wave = tid >> 6, lane = tid & 63;
  const int wm = wave >> 1, wn = wave & 1;
  const int n  = blockIdx.y;
  const int b0 = blockIdx.x * 64;

  const int r  = tid >> 2;
  const int cs = (tid & 3) ^ hsw(r);

  const float* ag = vflat + ((size_t)(n * MB_ + b0 + r)) * 1024 + (tid & 3) * 8;
  const int awOff = r * 32 + cs * 8;
  const bf16* bg = WvT + (size_t)n * 131072 + (size_t)r * 1024 + cs * 8;
  const int bOff = wave * 1024;

  f32x4 ra[2][2];

  #define LOADA(t, bi)  { const float* p = ag + (t) * 32;                    \
                          ra[bi][0] = *(const f32x4*)p;                      \
                          ra[bi][1] = *(const f32x4*)(p + 4); }
  #define GLOADB(t, bi) { const bf16* p = bg + (size_t)(t) * 32;             \
                          char* d = (char*)Bb[bi] + bOff;                    \
                          gload_lds16(p, d);                                 \
                          gload_lds16(p + 64 * 1024, d + 4096); }
  #define WRITEA(bi, dst) { f32x4 f0 = ra[bi][0], f1 = ra[bi][1];            \
    bf16x8 h = { (bf16)f0.x, (bf16)f0.y, (bf16)f0.z, (bf16)f0.w,             \
                 (bf16)f1.x, (bf16)f1.y, (bf16)f1.z, (bf16)f1.w };           \
    *(bf16x8*)&Ab[dst][awOff] = h; }

  LOADA(0, 0); GLOADB(0, 0); LOADA(1, 1); GLOADB(1, 1);
  WRITEA(0, 0);
  asm volatile("s_waitcnt vmcnt(4)" ::: "memory");
  asm volatile("s_waitcnt lgkmcnt(0)" ::: "memory");
  __builtin_amdgcn_s_barrier();
  __builtin_amdgcn_sched_barrier(0);

  f32x4 acc[2][4] = {};
  const int krow = lane & 15;
  const int cch  = lane >> 4;
  const int swoff = ((cch ^ hsw(krow)) << 4);

  #pragma unroll 2
  for (int t = 0; t < 32; ++t) {
    bf16x8 af[2], bfr[4];
    #pragma unroll
    for (int i = 0; i < 2; ++i)
      af[i] = *(const bf16x8*)((const char*)Ab[t & 1] + (wm * 32 + i * 16 + krow) * 64 + swoff);
    #pragma unroll
    for (int j = 0; j < 4; ++j)
      bfr[j] = *(const bf16x8*)((const char*)Bb[t % 3] + (wn * 64 + j * 16 + krow) * 64 + swoff);

    if (t < 31) WRITEA((t + 1) & 1, (t + 1) & 1);
    if (t < 30) { LOADA(t + 2, t & 1); GLOADB(t + 2, (t + 2) % 3); }

    #pragma unroll
    for (int i = 0; i < 2; ++i)
      #pragma unroll
      for (int j = 0; j < 4; ++j)
        acc[i][j] = __builtin_amdgcn_mfma_f32_16x16x32_bf16(af[i], bfr[j], acc[i][j], 0, 0, 0);

    if (t < 31) {
      asm volatile("s_waitcnt lgkmcnt(0)" ::: "memory");
      if (t < 30)       { asm volatile("s_waitcnt vmcnt(4)" ::: "memory"); }
      else              { asm volatile("s_waitcnt vmcnt(0)" ::: "memory"); }
      __builtin_amdgcn_s_barrier();
      __builtin_amdgcn_sched_barrier(0);
    }
  }
  #undef LOADA
  #undef GLOADB
  #undef WRITEA

  // epilogue: scatter v_s[n][b][t] -> A2 (torch raw-reshape layout)
  #pragma unroll
  for (int i = 0; i < 2; ++i) {
    #pragma unroll
    for (int j = 0; j < 4; ++j) {
      int t = wn * 64 + j * 16 + (lane & 15);
      #pragma unroll
      for (int rr = 0; rr < 4; ++rr) {
        int b = b0 + wm * 32 + i * 16 + (lane >> 4) * 4 + rr;
        size_t off = ((size_t)(n * 512 + (b >> 3))) * 1024 + (size_t)(b & 7) * 128 + t;
        A2[off] = (bf16)acc[i][j][rr];
      }
    }
  }
}

// ---------------------------------------------------------------------------
// GEMM2 (best-of-session, round-4 schedule): x = A2 @ PW^T + pb.
// Tile 256x256, BK=32, 4 LDS buffers, 2-deep staging, counted vmcnt(4),
// 2 phases per sub-tile with setprio'd MFMA clusters.
template<bool ZB>
__global__ __launch_bounds__(512, 2) void gemm2p_kernel(
    const bf16* __restrict__ A2, const bf16* __restrict__ PW,
    const float* __restrict__ pb, void* __restrict__ xoutp)
{
  __shared__ __align__(16) bf16 As[4][8192];  // [buf][256*32]
  __shared__ __align__(16) bf16 Bs[4][8192];

  const int tid  = threadIdx.x;
  const int w    = tid >> 6;
  const int lane = tid & 63;
  const int wm   = w >> 2;       // 0..1
  const int wn   = w & 3;        // 0..3

  const int bid   = blockIdx.x;          // 0..511
  const int x     = bid & 7;
  const int local = bid >> 3;            // 0..63
  const int mt    = local & 15;
  const int nt    = x * 4 + (local >> 4);
  const int m0    = mt * 256;
  const int n0    = nt * 256;

  const int rS = tid >> 2;
  const int cS = (tid & 3) ^ hsw(rS);
  const char* aG0 = (const char*)A2 + (size_t)(m0 + rS) * 2048 + cS * 16;
  const char* aG1 = aG0 + (size_t)128 * 2048;
  const char* bG0 = (const char*)PW + (size_t)(n0 + rS) * 2048 + cS * 16;
  const char* bG1 = bG0 + (size_t)128 * 2048;

  #define STAGE_A(t) { char* d = (char*)As[(t) & 3] + tid * 16;            \
                       gload_lds16(aG0 + (t) * 64, d);                      \
                       gload_lds16(aG1 + (t) * 64, d + 8192); }
  #define STAGE_B(t) { char* d = (char*)Bs[(t) & 3] + tid * 16;            \
                       gload_lds16(bG0 + (t) * 64, d);                      \
                       gload_lds16(bG1 + (t) * 64, d + 8192); }

  // prologue: tiles 0 and 1 (8 loads); wait tile 0 (4 in flight)
  STAGE_A(0); STAGE_B(0); STAGE_A(1); STAGE_B(1);
  asm volatile("s_waitcnt vmcnt(4)" ::: "memory");
  __builtin_amdgcn_sched_barrier(0);
  __builtin_amdgcn_s_barrier();

  f32x4 acc[8][4] = {};
  const int fr = lane & 15;
  const int g  = lane >> 4;
  const int swoff = ((g ^ hsw(fr)) << 4);
  const int aRd = (wm * 128 + fr) * 64 + swoff;
  const int bRd = (wn * 64  + fr) * 64 + swoff;

  #pragma unroll 4
  for (int t = 0; t < 32; ++t) {
    const char* pA = (const char*)As[t & 3] + aRd;
    const char* pB = (const char*)Bs[t & 3] + bRd;

    // ---- phase 1: A m0-3 + B reads, stage A(t+2), MFMA Q0 ----
    bf16x8 a[4], b[4];
    #pragma unroll
    for (int m = 0; m < 4; ++m) a[m] = *(const bf16x8*)(pA + m * 1024);
    #pragma unroll
    for (int n = 0; n < 4; ++n) b[n] = *(const bf16x8*)(pB + n * 1024);
    if (t < 30) STAGE_A(t + 2);
    __builtin_amdgcn_s_barrier();
    __builtin_amdgcn_s_setprio(1);
    #pragma unroll
    for (int m = 0; m < 4; ++m)
      #pragma unroll
      for (int n = 0; n < 4; ++n)
        acc[m][n] = __builtin_amdgcn_mfma_f32_16x16x32_bf16(a[m], b[n], acc[m][n], 0, 0, 0);
    __builtin_amdgcn_s_setprio(0);
    __builtin_amdgcn_s_barrier();

    // ---- phase 2: A m4-7 reads, stage B(t+2), counted vmcnt, MFMA Q1 ----
    bf16x8 a2[4];
    #pragma unroll
    for (int m = 0; m < 4; ++m) a2[m] = *(const bf16x8*)(pA + (4 + m) * 1024);
    if (t < 30) STAGE_B(t + 2);
    __builtin_amdgcn_s_barrier();
    __builtin_amdgcn_s_setprio(1);
    #pragma unroll
    for (int m = 0; m < 4; ++m)
      #pragma unroll
      for (int n = 0; n < 4; ++n)
        acc[4 + m][n] = __builtin_amdgcn_mfma_f32_16x16x32_bf16(a2[m], b[n], acc[4 + m][n], 0, 0, 0);
    __builtin_amdgcn_s_setprio(0);
    if (t < 30)       { asm volatile("s_waitcnt vmcnt(4)" ::: "memory"); }
    else if (t == 30) { asm volatile("s_waitcnt vmcnt(0)" ::: "memory"); }
    __builtin_amdgcn_sched_barrier(0);
    __builtin_amdgcn_s_barrier();
  }
  #undef STAGE_A
  #undef STAGE_B

  // epilogue: x = acc + pb -> bf16 ws (or f32 d_out)
  #pragma unroll
  for (int m = 0; m < 8; ++m) {
    #pragma unroll
    for (int n = 0; n < 4; ++n) {
      int nn = n0 + wn * 64 + n * 16 + fr;
      float pbn = pb[nn];
      #pragma unroll
      for (int r = 0; r < 4; ++r) {
        int mm = m0 + wm * 128 + m * 16 + g * 4 + r;
        size_t off = (size_t)mm * 8192 + nn;
        float val = acc[m][n][r] + pbn;
        if (ZB) ((bf16*)xoutp)[off] = (bf16)val;
        else    ((float*)xoutp)[off] = val;
      }
    }
  }
}

// ---------------------------------------------------------------------------
// LN over 1024-wide rows: x = z + v(residual); ddof=1, eps outside sqrt.
template<bool ZB>
__global__ __launch_bounds__(256) void ln_kernel(
    const void* zin, const float* __restrict__ vres,
    const float* __restrict__ gamma, const float* __restrict__ beta,
    float* outp)
{
  __shared__ float red[16];
  const int row = blockIdx.x;
  const int tid = threadIdx.x;
  const size_t base = (size_t)row * 1024 + tid * 4;

  float4 rv = *(const float4*)&vres[base];
  float4 x;
  if (ZB) {
    bf16x4 zb4 = *(const bf16x4*)((const bf16*)zin + base);
    x.x = (float)zb4[0] + rv.x; x.y = (float)zb4[1] + rv.y;
    x.z = (float)zb4[2] + rv.z; x.w = (float)zb4[3] + rv.w;
  } else {
    float4 zf = *(const float4*)((const float*)zin + base);
    x.x = zf.x + rv.x; x.y = zf.y + rv.y; x.z = zf.z + rv.z; x.w = zf.w + rv.w;
  }

  float s  = x.x + x.y + x.z + x.w;
  float ss = x.x * x.x + x.y * x.y + x.z * x.z + x.w * x.w;
  #pragma unroll
  for (int m = 32; m >= 1; m >>= 1) {
    s  += __shfl_xor(s,  m, 64);
    ss += __shfl_xor(ss, m, 64);
  }
  const int wave = tid >> 6, lane = tid & 63;
  if (lane == 0) { red[wave] = s; red[wave + 8] = ss; }
  __syncthreads();
  float S  = red[0] + red[1] + red[2] + red[3];
  float SS = red[8] + red[9] + red[10] + red[11];
  float mu  = S * (1.0f / 1024.0f);
  float var = (SS - 1024.0f * mu * mu) * (1.0f / 1023.0f);
  var = var < 0.0f ? 0.0f : var;
  float rs = 1.0f / (sqrtf(var) + 1e-3f);
  float4 gmv = *(const float4*)&gamma[tid * 4];
  float4 be  = *(const float4*)&beta[tid * 4];
  float4 y;
  y.x = (x.x - mu) * rs * gmv.x + be.x;
  y.y = (x.y - mu) * rs * gmv.y + be.y;
  y.z = (x.z - mu) * rs * gmv.z + be.z;
  y.w = (x.w - mu) * rs * gmv.w + be.w;
  *(float4*)&outp[base] = y;
}

// ---------------------------------------------------------------------------
extern "C" void kernel_launch(void* const* d_in, const int* in_sizes, int n_in,
                              void* d_out, int out_size, void* d_ws, size_t ws_size,
                              hipStream_t stream) {
  const float* v     = (const float*)d_in[2];
  const float* wvs   = (const float*)d_in[5];
  const float* pw    = (const float*)d_in[6];
  const float* pb    = (const float*)d_in[7];
  const float* gamma = (const float*)d_in[8];
  const float* beta  = (const float*)d_in[9];
  float* out = (float*)d_out;

  // ws: PW bf16 16M | WvT bf16 2M | A2 bf16 8M | x bf16 64M
  const size_t OFF_WVT = 16777216;
  const size_t OFF_A2  = OFF_WVT + 2097152;
  const size_t OFF_X   = OFF_A2 + 8388608;
  const size_t NEED_ZB = OFF_X + 67108864;

  bf16* PWb = (bf16*)d_ws;
  bf16* WvT = (bf16*)((char*)d_ws + OFF_WVT);
  bf16* A2  = (bf16*)((char*)d_ws + OFF_A2);
  const bool zb = (ws_size >= NEED_ZB);
  void* xbuf = zb ? (void*)((char*)d_ws + OFF_X) : (void*)out;

  hipLaunchKernelGGL(prep_kernel, dim3(12416), dim3(256), 0, stream, pw, PWb, wvs, WvT, out);
  hipLaunchKernelGGL(gemm1p_kernel, dim3(64, 8), dim3(256), 0, stream, v, WvT, A2);
  if (zb) {
    hipLaunchKernelGGL((gemm2p_kernel<true>),  dim3(512), dim3(512), 0, stream, A2, PWb, pb, xbuf);
    hipLaunchKernelGGL((ln_kernel<true>),      dim3(32768), dim3(256), 0, stream, xbuf, v, gamma, beta, out);
  } else {
    hipLaunchKernelGGL((gemm2p_kernel<false>), dim3(512), dim3(512), 0, stream, A2, PWb, pb, xbuf);
    hipLaunchKernelGGL((ln_kernel<false>),     dim3(32768), dim3(256), 0, stream, xbuf, v, gamma, beta, out);
  }
}